// Round 2
// baseline (474.770 us; speedup 1.0000x reference)
//
#include <hip/hip_runtime.h>
#include <math.h>

// SSIM loss, fused single-pass. fp32 [32,1,1024,1024] x2 -> scalar.
// Separable 11x11 Gaussian of 5 fields {a,b,a2,b2,ab}:
//  - LDS row staging with images INTERLEAVED as float2 (a,b) -> packed v_pk_fma_f32
//    for the (mu1,mu2) and (Saa,Sbb) convolutions.
//  - 2 output cols per thread: per-element products (a2,b2,ab) computed once,
//    LDS reads are 6 aligned ds_read_b128 per step per thread.
//  - vertical pass: 11-slot register accumulator ring, static mod-11 via unroll.
// launch_bounds(256,2): cap 256 VGPR so the ring stays in VGPRs (round 1's
// (256,4) forced it into AGPRs -> v_accvgpr churn, 2.3x VALU bloat).

typedef float v2f __attribute__((ext_vector_type(2)));
typedef float v4f __attribute__((ext_vector_type(4)));

#define IMG_W 1024
#define IMG_H 1024
#define NIMG  32
#define TW    512
#define TH    64
#define HALO  5
#define KW    11
#define ROWS  (TH + 2*HALO)   // 74 useful steps
#define STEPS 77              // 7*11, last 3 steps are dead (not emitted)
#define SBW   (TW + 2*HALO)   // 522 staged elements per row
#define SBP   532             // padded stride (even -> 16B-aligned rows)

#define C1f (0.01f * 0.01f)
#define C2f (0.03f * 0.03f)

struct GW { float w[KW]; };

__device__ __forceinline__ v2f splat2(float x) { v2f r; r.x = x; r.y = x; return r; }

__global__ __launch_bounds__(256, 2)
void ssim_main(const float* __restrict__ img1, const float* __restrict__ img2,
               double* __restrict__ acc_out, GW gw)
{
    alignas(16) __shared__ v2f sb[2][SBP];
    __shared__ float wsum[4];

    const int tid = threadIdx.x;
    const int c0 = blockIdx.x * TW;
    const int r0 = blockIdx.y * TH;
    const size_t imgoff = (size_t)blockIdx.z * (IMG_W * IMG_H);
    const float* p1 = img1 + imgoff;
    const float* p2 = img2 + imgoff;

    float w[KW];
#pragma unroll
    for (int i = 0; i < KW; ++i) w[i] = gw.w[i];

    // accumulator rings: [col][slot]; mu=(m1,m2) sq=(Saa,Sbb) ab=Sab
    v2f accmu[2][KW], accsq[2][KW];
    float accab[2][KW];
#pragma unroll
    for (int c = 0; c < 2; ++c)
#pragma unroll
        for (int j = 0; j < KW; ++j) {
            accmu[c][j] = splat2(0.f); accsq[c][j] = splat2(0.f); accab[c][j] = 0.f;
        }

    float lsum = 0.0f;

    // Stage one padded input row: LDS[e] = (img1, img2) at global col c0-5+e.
    auto load_row = [&](int s, int buf) {
        const int gr = r0 + s - HALO;
        const bool rok = ((unsigned)gr < (unsigned)IMG_H);
        const float* row1 = p1 + (size_t)gr * IMG_W;
        const float* row2 = p2 + (size_t)gr * IMG_W;
#pragma unroll
        for (int e0 = 0; e0 < SBW; e0 += 256) {
            int e = e0 + tid;
            if (e0 + 256 <= SBW || e < SBW) {
                int gc = c0 - HALO + e;
                bool ok = rok && ((unsigned)gc < (unsigned)IMG_W);
                v2f t; t.x = ok ? row1[gc] : 0.f; t.y = ok ? row2[gc] : 0.f;
                sb[buf][e] = t;
            }
        }
    };

    load_row(0, 0);

    for (int so = 0; so < STEPS / KW; ++so) {
#pragma unroll
        for (int u = 0; u < KW; ++u) {
            const int s = so * KW + u;
            __syncthreads();
            if (s + 1 < ROWS) load_row(s + 1, (s + 1) & 1);

            // thread covers elements 2*tid .. 2*tid+11 (cols A=2t, B=2t+1)
            const v4f* src = (const v4f*)(&sb[s & 1][0]);
            v4f q[6];
#pragma unroll
            for (int i = 0; i < 6; ++i) q[i] = src[tid + i];

            v2f E[12];
#pragma unroll
            for (int i = 0; i < 6; ++i) {
                E[2 * i]     = __builtin_shufflevector(q[i], q[i], 0, 1);
                E[2 * i + 1] = __builtin_shufflevector(q[i], q[i], 2, 3);
            }

            // per-element products, once per element
            v2f  sq[12];
            float ab[12];
#pragma unroll
            for (int j = 0; j < 12; ++j) {
                sq[j] = E[j] * E[j];
                ab[j] = E[j].x * E[j].y;
            }

            // horizontal 11-tap conv for both cols (packed over the image pair)
            v2f hmu0 = splat2(0.f), hmu1 = splat2(0.f);
            v2f hsq0 = splat2(0.f), hsq1 = splat2(0.f);
            float hab0 = 0.f, hab1 = 0.f;
#pragma unroll
            for (int i = 0; i < KW; ++i) {
                v2f wi = splat2(w[i]);
                hmu0 += wi * E[i];     hsq0 += wi * sq[i];     hab0 += w[i] * ab[i];
                hmu1 += wi * E[i + 1]; hsq1 += wi * sq[i + 1]; hab1 += w[i] * ab[i + 1];
            }

            // vertical ring accumulate; slot j fresh-starts when k==0 (overwrite)
#pragma unroll
            for (int j = 0; j < KW; ++j) {
                const int k = (u - j + KW) % KW;   // compile-time after unroll
                const v2f  wk2 = splat2(w[k]);
                const float wk = w[k];
                if (k == 0) {
                    accmu[0][j] = wk2 * hmu0; accsq[0][j] = wk2 * hsq0; accab[0][j] = wk * hab0;
                    accmu[1][j] = wk2 * hmu1; accsq[1][j] = wk2 * hsq1; accab[1][j] = wk * hab1;
                } else {
                    accmu[0][j] += wk2 * hmu0; accsq[0][j] += wk2 * hsq0; accab[0][j] += wk * hab0;
                    accmu[1][j] += wk2 * hmu1; accsq[1][j] += wk2 * hsq1; accab[1][j] += wk * hab1;
                }
            }

            // output row r = s-10 completed in slot (u+1)%11
            if (s >= 10 && s <= TH + 9) {
                const int je = (u + 1) % KW;
#pragma unroll
                for (int c = 0; c < 2; ++c) {
                    float mu1 = accmu[c][je].x, mu2 = accmu[c][je].y;
                    float caa = accsq[c][je].x, cbb = accsq[c][je].y;
                    float cab = accab[c][je];
                    float mu1s = mu1 * mu1, mu2s = mu2 * mu2, mu12 = mu1 * mu2;
                    float sg1 = caa - mu1s, sg2 = cbb - mu2s, sg12 = cab - mu12;
                    float num = (2.0f * mu12 + C1f) * (2.0f * sg12 + C2f);
                    float den = (mu1s + mu2s + C1f) * (sg1 + sg2 + C2f);
                    lsum += num * __builtin_amdgcn_rcpf(den);
                }
            }
        }
    }

    // block reduction: wave shuffle then LDS across the 4 waves
    float v = lsum;
#pragma unroll
    for (int off = 32; off > 0; off >>= 1) v += __shfl_down(v, off);
    __syncthreads();
    if ((tid & 63) == 0) wsum[tid >> 6] = v;
    __syncthreads();
    if (tid == 0) {
        float bsum = wsum[0] + wsum[1] + wsum[2] + wsum[3];
        atomicAdd(acc_out, (double)bsum);
    }
}

__global__ void ssim_finalize(const double* __restrict__ acc, float* __restrict__ out)
{
    out[0] = 1.0f - (float)(acc[0] * (1.0 / ((double)NIMG * IMG_W * IMG_H)));
}

extern "C" void kernel_launch(void* const* d_in, const int* in_sizes, int n_in,
                              void* d_out, int out_size, void* d_ws, size_t ws_size,
                              hipStream_t stream)
{
    const float* img1 = (const float*)d_in[0];
    const float* img2 = (const float*)d_in[1];
    float* out = (float*)d_out;
    double* accbuf = (double*)d_ws;

    // Gaussian weights exactly as the reference: exp in f64, cast f32, normalize
    GW gw;
    {
        float g[KW];
        double s = 0.0;
        for (int i = 0; i < KW; ++i) {
            int x = i - KW / 2;
            g[i] = (float)exp(-(double)(x * x) / (2.0 * 1.5 * 1.5));
            s += (double)g[i];
        }
        for (int i = 0; i < KW; ++i) gw.w[i] = (float)((double)g[i] / s);
    }

    hipMemsetAsync(accbuf, 0, sizeof(double), stream);
    dim3 grid(IMG_W / TW, IMG_H / TH, NIMG);
    ssim_main<<<grid, 256, 0, stream>>>(img1, img2, accbuf, gw);
    ssim_finalize<<<1, 1, 0, stream>>>(accbuf, out);
}

// Round 3
// 397.009 us; speedup vs baseline: 1.1959x; 1.1959x over previous
//
#include <hip/hip_runtime.h>
#include <math.h>

// SSIM loss, fused single-pass. fp32 [32,1,1024,1024] x2 -> scalar.
// Separable 11x11 Gaussian of 5 fields {a,b,a2,b2,ab}.
// Round-3 structure:
//  - 1 output col/thread (ring state 55 floats fits VGPRs; round 1/2's larger
//    state spilled to AGPRs -> ~2.5x VALU bloat).
//  - Register-staged pipeline: global loads for row s+2 issued at phase s,
//    committed to LDS at phase s+1. The ds_write waits on loads issued a full
//    phase earlier, so per-phase exposed HBM latency is ~200cy, not ~2700cy
//    (round 2 did load->waitcnt->ds_write inline, serializing 2-3 HBM round
//    trips per barrier phase -> 4900cy phases, VALUBusy 32%).
//  - LDS rows hold (img1,img2) interleaved v2f -> packed v_pk_fma_f32 for the
//    (mu1,mu2) and (Saa,Sbb) convolutions.
//  - Vertical conv: 11-slot register ring, static mod-11 via unroll.
// Tile 256 cols x 128 rows; grid 4x8x32 = 1024 blocks = 4/CU in one round.

typedef float v2f __attribute__((ext_vector_type(2)));

#define IMG_W 1024
#define IMG_H 1024
#define NIMG  32
#define TW    256
#define TH    128
#define HALO  5
#define KW    11
#define ROWS  (TH + 2*HALO)   // 138 staged rows
#define NSO   13              // 13*11 = 143 unrolled steps, tail guarded off
#define SBP   272             // LDS row stride in v2f (266 used, padded)

#define C1f (0.01f * 0.01f)
#define C2f (0.03f * 0.03f)

struct GW { float w[KW]; };

__global__ __launch_bounds__(256, 2)
void ssim_main(const float* __restrict__ img1, const float* __restrict__ img2,
               double* __restrict__ acc_out, GW gw)
{
    alignas(16) __shared__ v2f sb[2][SBP];
    __shared__ float wsum[4];

    const int tid = threadIdx.x;
    const int c0 = blockIdx.x * TW;
    const int r0 = blockIdx.y * TH;
    const size_t imgoff = (size_t)blockIdx.z * (size_t)(IMG_W * IMG_H);
    const float* p1 = img1 + imgoff;
    const float* p2 = img2 + imgoff;

    // column predicates (uniform over rows)
    const int  gc_main  = c0 - HALO + tid;
    const bool cok_main = ((unsigned)gc_main < (unsigned)IMG_W);
    const int  gc_halo  = c0 - HALO + TW + tid;              // only tid<10 uses
    const bool cok_halo = (tid < 2 * HALO) && ((unsigned)gc_halo < (unsigned)IMG_W);

    float w[KW];
#pragma unroll
    for (int i = 0; i < KW; ++i) w[i] = gw.w[i];

    // vertical ring: mu=(m1,m2), sq=(Saa,Sbb), ab=Sab  -> 55 floats
    v2f accmu[KW], accsq[KW];
    float accab[KW];
#pragma unroll
    for (int j = 0; j < KW; ++j) {
        accmu[j] = (v2f)(0.f); accsq[j] = (v2f)(0.f); accab[j] = 0.f;
    }

    float lsum = 0.0f;

    // staging registers: [a_main, b_main, a_halo, b_halo] for one row
    float st[4];

    auto issue = [&](int s, float v[4]) {   // global -> regs for staged row s
        const int gr = r0 + s - HALO;
        const bool rok = ((unsigned)gr < (unsigned)IMG_H);
        const float* row1 = p1 + (size_t)gr * IMG_W;
        const float* row2 = p2 + (size_t)gr * IMG_W;
        const bool okm = rok && cok_main;
        const bool okh = rok && cok_halo;
        v[0] = okm ? row1[gc_main] : 0.f;
        v[1] = okm ? row2[gc_main] : 0.f;
        v[2] = okh ? row1[gc_halo] : 0.f;
        v[3] = okh ? row2[gc_halo] : 0.f;
    };
    auto commit = [&](int s, const float v[4]) {  // regs -> LDS buffer s&1
        const int buf = s & 1;
        v2f t; t.x = v[0]; t.y = v[1];
        sb[buf][tid] = t;
        if (tid < 2 * HALO) { v2f t2; t2.x = v[2]; t2.y = v[3]; sb[buf][TW + tid] = t2; }
    };

    issue(0, st); commit(0, st);   // row 0 straight to LDS
    issue(1, st);                  // row 1 in flight in regs

    for (int so = 0; so < NSO; ++so) {
#pragma unroll
        for (int u = 0; u < KW; ++u) {
            const int s = so * KW + u;
            if (s < ROWS) {                    // uniform guard (tail steps dead)
                __syncthreads();               // phase s-1 reads done; buf (s+1)&1 free
                if (s + 1 < ROWS) commit(s + 1, st);  // regs (1 phase old) -> LDS
                if (s + 2 < ROWS) issue(s + 2, st);   // next row into regs

                // horizontal 11-tap conv of the 5 fields, packed over (img1,img2)
                const v2f* b = &sb[s & 1][0];
                v2f hmu = (v2f)(0.f), hsq = (v2f)(0.f);
                float hab = 0.f;
#pragma unroll
                for (int i = 0; i < KW; ++i) {
                    v2f E = b[tid + i];
                    v2f sq = E * E;
                    float ab = E.x * E.y;
                    v2f wi; wi.x = w[i]; wi.y = w[i];
                    hmu += wi * E;
                    hsq += wi * sq;
                    hab += w[i] * ab;
                }

                // vertical ring accumulate; slot j fresh-starts when k==0
#pragma unroll
                for (int j = 0; j < KW; ++j) {
                    const int k = (u - j + KW) % KW;   // compile-time after unroll
                    v2f wk; wk.x = w[k]; wk.y = w[k];
                    if (k == 0) {
                        accmu[j] = wk * hmu; accsq[j] = wk * hsq; accab[j] = w[k] * hab;
                    } else {
                        accmu[j] += wk * hmu; accsq[j] += wk * hsq; accab[j] += w[k] * hab;
                    }
                }

                // output row r = s-10 completes in slot (u+1)%11
                if (s >= 10) {
                    const int je = (u + 1) % KW;
                    v2f mu = accmu[je];
                    v2f sqv = accsq[je];
                    float cab = accab[je];
                    v2f mus = mu * mu;                 // (mu1^2, mu2^2)
                    float mu12 = mu.x * mu.y;
                    v2f sg = sqv - mus;                // (sigma1^2, sigma2^2)
                    float sg12 = cab - mu12;
                    float num = (2.0f * mu12 + C1f) * (2.0f * sg12 + C2f);
                    float den = (mus.x + mus.y + C1f) * (sg.x + sg.y + C2f);
                    lsum += num * __builtin_amdgcn_rcpf(den);
                }
            }
        }
    }

    // block reduction: wave shuffle then LDS across the 4 waves
    float v = lsum;
#pragma unroll
    for (int off = 32; off > 0; off >>= 1) v += __shfl_down(v, off);
    __syncthreads();
    if ((tid & 63) == 0) wsum[tid >> 6] = v;
    __syncthreads();
    if (tid == 0) {
        float bsum = wsum[0] + wsum[1] + wsum[2] + wsum[3];
        atomicAdd(acc_out, (double)bsum);
    }
}

__global__ void ssim_finalize(const double* __restrict__ acc, float* __restrict__ out)
{
    out[0] = 1.0f - (float)(acc[0] * (1.0 / ((double)NIMG * IMG_W * IMG_H)));
}

extern "C" void kernel_launch(void* const* d_in, const int* in_sizes, int n_in,
                              void* d_out, int out_size, void* d_ws, size_t ws_size,
                              hipStream_t stream)
{
    const float* img1 = (const float*)d_in[0];
    const float* img2 = (const float*)d_in[1];
    float* out = (float*)d_out;
    double* accbuf = (double*)d_ws;

    // Gaussian weights exactly as the reference: exp in f64, cast f32, normalize
    GW gw;
    {
        float g[KW];
        double s = 0.0;
        for (int i = 0; i < KW; ++i) {
            int x = i - KW / 2;
            g[i] = (float)exp(-(double)(x * x) / (2.0 * 1.5 * 1.5));
            s += (double)g[i];
        }
        for (int i = 0; i < KW; ++i) gw.w[i] = (float)((double)g[i] / s);
    }

    hipMemsetAsync(accbuf, 0, sizeof(double), stream);
    dim3 grid(IMG_W / TW, IMG_H / TH, NIMG);
    ssim_main<<<grid, 256, 0, stream>>>(img1, img2, accbuf, gw);
    ssim_finalize<<<1, 1, 0, stream>>>(accbuf, out);
}